// Round 1
// baseline (235.911 us; speedup 1.0000x reference)
//
#include <hip/hip_runtime.h>
#include <hip/hip_bf16.h>
#include <cmath>

#define NB 16384   // batch rows
#define NK 512     // in features
#define NO 1024    // out features (centres)
#define NC 5       // classes

typedef float f32x4 __attribute__((ext_vector_type(4)));
typedef short s16x8 __attribute__((ext_vector_type(8)));

__device__ inline short f2bf(float f) {
    union { __hip_bfloat16 h; short s; } u;
    u.h = __float2bfloat16(f);
    return u.s;
}

// ---------------------------------------------------------------------------
// Kernel 1: row sum-of-squares for inputs (x2) and centres (c2).
// One wave per row: 512 f32 = 8 per lane (two float4 loads), shuffle reduce.
// ---------------------------------------------------------------------------
__global__ void prep_kernel(const float* __restrict__ x, const float* __restrict__ c,
                            float* __restrict__ x2, float* __restrict__ c2) {
    int gw   = (blockIdx.x * blockDim.x + threadIdx.x) >> 6;
    int lane = threadIdx.x & 63;
    if (gw >= NB + NO) return;
    const float* src = (gw < NB) ? (x + (size_t)gw * NK)
                                 : (c + (size_t)(gw - NB) * NK);
    f32x4 v0 = *(const f32x4*)(src + lane * 8);
    f32x4 v1 = *(const f32x4*)(src + lane * 8 + 4);
    float s = 0.f;
#pragma unroll
    for (int j = 0; j < 4; ++j) s += v0[j] * v0[j] + v1[j] * v1[j];
#pragma unroll
    for (int off = 1; off < 64; off <<= 1) s += __shfl_xor(s, off);
    if (lane == 0) {
        if (gw < NB) x2[gw] = s;
        else         c2[gw - NB] = s;
    }
}

// ---------------------------------------------------------------------------
// Kernel 2: out[b][n] = fc_b[n]  (d_out is poisoned before every timed call;
// the GEMM kernel then atomicAdds basis @ fc_w^T contributions on top).
// ---------------------------------------------------------------------------
__global__ void init_out(float* __restrict__ out, const float* __restrict__ fcb) {
    int i = blockIdx.x * blockDim.x + threadIdx.x;
    if (i < NB * NC) out[i] = fcb[i % NC];
}

// ---------------------------------------------------------------------------
// Kernel 3: fused distance-GEMM + RBF basis + 5-class reduction.
// 128x128 tile, BK=32, 256 threads = 4 waves (2x2), each wave 64x64 via
// 4x4 fragments of v_mfma_f32_16x16x32_bf16. Reg-staged f32->bf16 to LDS.
// ---------------------------------------------------------------------------
__global__ __launch_bounds__(256)
void rbf_gemm(const float* __restrict__ X, const float* __restrict__ Cn,
              const float* __restrict__ x2, const float* __restrict__ c2,
              const float* __restrict__ ls, const float* __restrict__ fcw,
              float* __restrict__ out) {
    // LDS: padded stride 40 shorts (80 B) -> ~2-way bank aliasing on b128 reads
    __shared__ short As[128 * 40];
    __shared__ short Bs[128 * 40];

    const int t    = threadIdx.x;
    const int lane = t & 63, wave = t >> 6;
    const int wr = wave >> 1, wc = wave & 1;      // 2x2 wave grid
    const int lc = lane & 15, kg = lane >> 4;     // fragment col / k-group
    const int bn = blockIdx.x, bm = blockIdx.y;

    // staging: thread t loads row t>>1, k-half t&1 (16 floats)
    const int srow = t >> 1, shalf = t & 1;
    const float* pA = X  + (size_t)(bm * 128 + srow) * NK + shalf * 16;
    const float* pB = Cn + (size_t)(bn * 128 + srow) * NK + shalf * 16;
    const int sbase = srow * 40 + shalf * 16;

    f32x4 ra[4], rb[4];
#pragma unroll
    for (int i = 0; i < 4; ++i) {
        ra[i] = *(const f32x4*)(pA + i * 4);
        rb[i] = *(const f32x4*)(pB + i * 4);
    }

    f32x4 acc[4][4];
#pragma unroll
    for (int i = 0; i < 4; ++i)
#pragma unroll
        for (int j = 0; j < 4; ++j)
#pragma unroll
            for (int k = 0; k < 4; ++k) acc[i][j][k] = 0.f;

    const short* Ab = As + (wr * 64 + lc) * 40 + kg * 8;
    const short* Bb = Bs + (wc * 64 + lc) * 40 + kg * 8;

    for (int kt = 0; kt < NK / 32; ++kt) {
        __syncthreads();   // previous tile fully consumed
        s16x8 va0, va1, vb0, vb1;
#pragma unroll
        for (int i = 0; i < 8; ++i) {
            va0[i] = f2bf(ra[i >> 2][i & 3]);
            va1[i] = f2bf(ra[2 + (i >> 2)][i & 3]);
            vb0[i] = f2bf(rb[i >> 2][i & 3]);
            vb1[i] = f2bf(rb[2 + (i >> 2)][i & 3]);
        }
        *(s16x8*)&As[sbase]     = va0;
        *(s16x8*)&As[sbase + 8] = va1;
        *(s16x8*)&Bs[sbase]     = vb0;
        *(s16x8*)&Bs[sbase + 8] = vb1;
        __syncthreads();

        if (kt + 1 < NK / 32) {   // prefetch next K-tile into regs (overlaps MFMA)
            const float* qA = pA + (kt + 1) * 32;
            const float* qB = pB + (kt + 1) * 32;
#pragma unroll
            for (int i = 0; i < 4; ++i) {
                ra[i] = *(const f32x4*)(qA + i * 4);
                rb[i] = *(const f32x4*)(qB + i * 4);
            }
        }

        s16x8 af[4], bfv[4];
#pragma unroll
        for (int mi = 0; mi < 4; ++mi) af[mi]  = *(const s16x8*)(Ab + mi * 16 * 40);
#pragma unroll
        for (int ni = 0; ni < 4; ++ni) bfv[ni] = *(const s16x8*)(Bb + ni * 16 * 40);
#pragma unroll
        for (int mi = 0; mi < 4; ++mi)
#pragma unroll
            for (int ni = 0; ni < 4; ++ni)
                acc[mi][ni] = __builtin_amdgcn_mfma_f32_16x16x32_bf16(
                    af[mi], bfv[ni], acc[mi][ni], 0, 0, 0);
    }

    // ---- epilogue: sq -> dist -> basis -> reduce over cols with fc_w ----
    // C layout (16x16x32): col = lane&15, row = (lane>>4)*4 + reg   [m89/m91]
    const int growb0 = bm * 128 + wr * 64 + kg * 4;  // + mi*16 + r
    const int gcol0  = bn * 128 + wc * 64 + lc;      // + ni*16

    float c2v[4], invs[4], w[4][5];
#pragma unroll
    for (int ni = 0; ni < 4; ++ni) {
        int gc = gcol0 + ni * 16;
        c2v[ni]  = c2[gc];
        invs[ni] = expf(-ls[gc]);          // 1/exp(log_sigma)
#pragma unroll
        for (int n = 0; n < 5; ++n) w[ni][n] = fcw[n * NO + gc];
    }

#pragma unroll
    for (int mi = 0; mi < 4; ++mi) {
        float rs[4][5];
#pragma unroll
        for (int r = 0; r < 4; ++r)
#pragma unroll
            for (int n = 0; n < 5; ++n) rs[r][n] = 0.f;

#pragma unroll
        for (int r = 0; r < 4; ++r) {
            float x2v = x2[growb0 + mi * 16 + r];
#pragma unroll
            for (int ni = 0; ni < 4; ++ni) {
                float sq    = fmaxf(x2v + c2v[ni] - 2.f * acc[mi][ni][r], 0.f);
                float dist  = sqrtf(sq) * invs[ni];
                float basis = expf(-dist * dist);
#pragma unroll
                for (int n = 0; n < 5; ++n) rs[r][n] += basis * w[ni][n];
            }
        }
        // reduce across the 16 fragment columns (lane bits 0..3)
#pragma unroll
        for (int off = 1; off < 16; off <<= 1)
#pragma unroll
            for (int r = 0; r < 4; ++r)
#pragma unroll
                for (int n = 0; n < 5; ++n) rs[r][n] += __shfl_xor(rs[r][n], off);

        if (lc == 0) {
#pragma unroll
            for (int r = 0; r < 4; ++r) {
                int grow = growb0 + mi * 16 + r;
#pragma unroll
                for (int n = 0; n < 5; ++n)
                    atomicAdd(&out[(size_t)grow * NC + n], rs[r][n]);
            }
        }
    }
}

// ---------------------------------------------------------------------------
extern "C" void kernel_launch(void* const* d_in, const int* in_sizes, int n_in,
                              void* d_out, int out_size, void* d_ws, size_t ws_size,
                              hipStream_t stream) {
    const float* X   = (const float*)d_in[0];   // [16384, 512]
    const float* Cn  = (const float*)d_in[1];   // [1024, 512]
    const float* ls  = (const float*)d_in[2];   // [1024]
    const float* fcw = (const float*)d_in[3];   // [5, 1024]
    const float* fcb = (const float*)d_in[4];   // [5]
    float* out = (float*)d_out;                 // [16384, 5]

    float* x2 = (float*)d_ws;                   // 16384 f32
    float* c2 = x2 + NB;                        // 1024 f32

    prep_kernel<<<(NB + NO) / 4, 256, 0, stream>>>(X, Cn, x2, c2);
    init_out<<<(NB * NC + 255) / 256, 256, 0, stream>>>(out, fcb);
    dim3 grid(NO / 128, NB / 128);
    rbf_gemm<<<grid, 256, 0, stream>>>(X, Cn, x2, c2, ls, fcw, out);
}

// Round 2
// 216.383 us; speedup vs baseline: 1.0902x; 1.0902x over previous
//
#include <hip/hip_runtime.h>
#include <hip/hip_bf16.h>
#include <cmath>

#define NB 16384   // batch rows
#define NK 512     // in features
#define NO 1024    // out features (centres)
#define NC 5       // classes

typedef float f32x4 __attribute__((ext_vector_type(4)));
typedef short s16x8 __attribute__((ext_vector_type(8)));

__device__ inline short f2bf(float f) {
    union { __hip_bfloat16 h; short s; } u;
    u.h = __float2bfloat16(f);
    return u.s;
}

// ---------------------------------------------------------------------------
// Kernel 1: fused row sum-of-squares (f32) + bf16 conversion of X and C.
// One wave per row: 512 f32 = 8 per lane. Reads 35 MB, writes 18 MB.
// ---------------------------------------------------------------------------
__global__ void prep_bf16(const float* __restrict__ x, const float* __restrict__ c,
                          short* __restrict__ xbf, short* __restrict__ cbf,
                          float* __restrict__ x2, float* __restrict__ c2) {
    int gw   = (blockIdx.x * blockDim.x + threadIdx.x) >> 6;
    int lane = threadIdx.x & 63;
    if (gw >= NB + NO) return;
    bool isX = gw < NB;
    const float* src = isX ? (x + (size_t)gw * NK) : (c + (size_t)(gw - NB) * NK);
    short*       dst = isX ? (xbf + (size_t)gw * NK) : (cbf + (size_t)(gw - NB) * NK);
    f32x4 v0 = *(const f32x4*)(src + lane * 8);
    f32x4 v1 = *(const f32x4*)(src + lane * 8 + 4);
    s16x8 o;
    float s = 0.f;
#pragma unroll
    for (int j = 0; j < 4; ++j) {
        s += v0[j] * v0[j] + v1[j] * v1[j];
        o[j]     = f2bf(v0[j]);
        o[4 + j] = f2bf(v1[j]);
    }
    *(s16x8*)(dst + lane * 8) = o;
#pragma unroll
    for (int off = 1; off < 64; off <<= 1) s += __shfl_xor(s, off);
    if (lane == 0) {
        if (isX) x2[gw] = s;
        else     c2[gw - NB] = s;
    }
}

// Standalone prep for the fallback path (no bf16 staging space in ws).
__global__ void prep_f32(const float* __restrict__ x, const float* __restrict__ c,
                         float* __restrict__ x2, float* __restrict__ c2) {
    int gw   = (blockIdx.x * blockDim.x + threadIdx.x) >> 6;
    int lane = threadIdx.x & 63;
    if (gw >= NB + NO) return;
    const float* src = (gw < NB) ? (x + (size_t)gw * NK)
                                 : (c + (size_t)(gw - NB) * NK);
    f32x4 v0 = *(const f32x4*)(src + lane * 8);
    f32x4 v1 = *(const f32x4*)(src + lane * 8 + 4);
    float s = 0.f;
#pragma unroll
    for (int j = 0; j < 4; ++j) s += v0[j] * v0[j] + v1[j] * v1[j];
#pragma unroll
    for (int off = 1; off < 64; off <<= 1) s += __shfl_xor(s, off);
    if (lane == 0) {
        if (gw < NB) x2[gw] = s;
        else         c2[gw - NB] = s;
    }
}

// ---------------------------------------------------------------------------
// Kernel 2: out[b][n] = fc_b[n]  (d_out is 0xAA-poisoned before every call).
// ---------------------------------------------------------------------------
__global__ void init_out(float* __restrict__ out, const float* __restrict__ fcb) {
    int i = blockIdx.x * blockDim.x + threadIdx.x;
    if (i < NB * NC) out[i] = fcb[i % NC];
}

// ---------------------------------------------------------------------------
// Shared epilogue: acc (A.C^T frags) -> sq -> basis -> 5-class reduce+atomic.
// C layout (16x16x32): col = lane&15, row = (lane>>4)*4 + reg   [m89/m91]
// ---------------------------------------------------------------------------
__device__ inline void rbf_epilogue(f32x4 acc[4][4],
                                    const float* __restrict__ x2,
                                    const float* __restrict__ c2,
                                    const float* __restrict__ ls,
                                    const float* __restrict__ fcw,
                                    float* __restrict__ out,
                                    int bm, int bn, int wr, int wc,
                                    int lc, int kg) {
    const int growb0 = bm * 128 + wr * 64 + kg * 4;  // + mi*16 + r
    const int gcol0  = bn * 128 + wc * 64 + lc;      // + ni*16

    float c2v[4], invs2[4], w[4][5];
#pragma unroll
    for (int ni = 0; ni < 4; ++ni) {
        int gc = gcol0 + ni * 16;
        c2v[ni]   = c2[gc];
        invs2[ni] = expf(-2.f * ls[gc]);   // 1/sigma^2; basis = exp(-sq/sigma^2)
#pragma unroll
        for (int n = 0; n < 5; ++n) w[ni][n] = fcw[n * NO + gc];
    }

#pragma unroll
    for (int mi = 0; mi < 4; ++mi) {
        float rs[4][5];
#pragma unroll
        for (int r = 0; r < 4; ++r)
#pragma unroll
            for (int n = 0; n < 5; ++n) rs[r][n] = 0.f;

#pragma unroll
        for (int r = 0; r < 4; ++r) {
            float x2v = x2[growb0 + mi * 16 + r];
#pragma unroll
            for (int ni = 0; ni < 4; ++ni) {
                float sq    = fmaxf(x2v + c2v[ni] - 2.f * acc[mi][ni][r], 0.f);
                float basis = expf(-sq * invs2[ni]);
#pragma unroll
                for (int n = 0; n < 5; ++n) rs[r][n] += basis * w[ni][n];
            }
        }
#pragma unroll
        for (int off = 1; off < 16; off <<= 1)
#pragma unroll
            for (int r = 0; r < 4; ++r)
#pragma unroll
                for (int n = 0; n < 5; ++n) rs[r][n] += __shfl_xor(rs[r][n], off);

        if (lc == 0) {
#pragma unroll
            for (int r = 0; r < 4; ++r) {
                int grow = growb0 + mi * 16 + r;
#pragma unroll
                for (int n = 0; n < 5; ++n)
                    atomicAdd(&out[(size_t)grow * NC + n], rs[r][n]);
            }
        }
    }
}

// ---------------------------------------------------------------------------
// Kernel 3 (main path): m97-structure GEMM on pre-converted bf16.
// 128x128 tile, BK=32, 4 waves (2x2), global_load_lds width-16 into linear
// LDS [128][32] shorts, 16 MFMA(16x16x32 bf16)/wave/K-step.
// ---------------------------------------------------------------------------
__global__ __launch_bounds__(256)
void rbf_gemm_bf16(const short* __restrict__ Abf, const short* __restrict__ Bbf,
                   const float* __restrict__ x2, const float* __restrict__ c2,
                   const float* __restrict__ ls, const float* __restrict__ fcw,
                   float* __restrict__ out) {
    __shared__ short As[128 * 32];
    __shared__ short Bs[128 * 32];

    const int t    = threadIdx.x;
    const int lane = t & 63, wave = t >> 6;
    const int wr = wave >> 1, wc = wave & 1;
    const int lc = lane & 15, kg = lane >> 4;
    const int bn = blockIdx.x, bm = blockIdx.y;

    // global_load_lds staging: issue j (j=0,1) covers rows [j*64, j*64+64).
    // thread t handles short index (j*256+t)*8 of the row-major [128][32] tile
    // -> row = j*64 + wave*16 + (lane>>2), kcol = (lane&3)*8.
    const int srow = wave * 16 + (lane >> 2);
    const int scol = (lane & 3) * 8;
    const short* gA = Abf + (size_t)(bm * 128 + srow) * NK + scol;
    const short* gB = Bbf + (size_t)(bn * 128 + srow) * NK + scol;
    // wave-uniform LDS base (bytes): j*4096 + wave*1024
    short* lA = As + wave * 512;   // + j*2048 (shorts)
    short* lB = Bs + wave * 512;

    f32x4 acc[4][4];
#pragma unroll
    for (int i = 0; i < 4; ++i)
#pragma unroll
        for (int j = 0; j < 4; ++j)
#pragma unroll
            for (int k = 0; k < 4; ++k) acc[i][j][k] = 0.f;

    const short* Ab = As + (wr * 64 + lc) * 32 + kg * 8;
    const short* Bb = Bs + (wc * 64 + lc) * 32 + kg * 8;

    for (int kt = 0; kt < NK / 32; ++kt) {
        __syncthreads();   // previous tile fully consumed
#pragma unroll
        for (int j = 0; j < 2; ++j) {
            __builtin_amdgcn_global_load_lds(
                (const __attribute__((address_space(1))) unsigned int*)(gA + (size_t)j * 64 * NK + kt * 32),
                (__attribute__((address_space(3))) unsigned int*)(lA + j * 2048),
                16, 0, 0);
            __builtin_amdgcn_global_load_lds(
                (const __attribute__((address_space(1))) unsigned int*)(gB + (size_t)j * 64 * NK + kt * 32),
                (__attribute__((address_space(3))) unsigned int*)(lB + j * 2048),
                16, 0, 0);
        }
        __syncthreads();   // compiler drains vmcnt(0) before s_barrier

        s16x8 af[4], bfv[4];
#pragma unroll
        for (int mi = 0; mi < 4; ++mi) af[mi]  = *(const s16x8*)(Ab + mi * 16 * 32);
#pragma unroll
        for (int ni = 0; ni < 4; ++ni) bfv[ni] = *(const s16x8*)(Bb + ni * 16 * 32);
#pragma unroll
        for (int mi = 0; mi < 4; ++mi)
#pragma unroll
            for (int ni = 0; ni < 4; ++ni)
                acc[mi][ni] = __builtin_amdgcn_mfma_f32_16x16x32_bf16(
                    af[mi], bfv[ni], acc[mi][ni], 0, 0, 0);
    }

    rbf_epilogue(acc, x2, c2, ls, fcw, out, bm, bn, wr, wc, lc, kg);
}

// ---------------------------------------------------------------------------
// Fallback (ws too small): round-1 kernel, f32 reg-staged. Known-correct.
// ---------------------------------------------------------------------------
__global__ __launch_bounds__(256)
void rbf_gemm_f32(const float* __restrict__ X, const float* __restrict__ Cn,
                  const float* __restrict__ x2, const float* __restrict__ c2,
                  const float* __restrict__ ls, const float* __restrict__ fcw,
                  float* __restrict__ out) {
    __shared__ short As[128 * 40];
    __shared__ short Bs[128 * 40];

    const int t    = threadIdx.x;
    const int lane = t & 63, wave = t >> 6;
    const int wr = wave >> 1, wc = wave & 1;
    const int lc = lane & 15, kg = lane >> 4;
    const int bn = blockIdx.x, bm = blockIdx.y;

    const int srow = t >> 1, shalf = t & 1;
    const float* pA = X  + (size_t)(bm * 128 + srow) * NK + shalf * 16;
    const float* pB = Cn + (size_t)(bn * 128 + srow) * NK + shalf * 16;
    const int sbase = srow * 40 + shalf * 16;

    f32x4 ra[4], rb[4];
#pragma unroll
    for (int i = 0; i < 4; ++i) {
        ra[i] = *(const f32x4*)(pA + i * 4);
        rb[i] = *(const f32x4*)(pB + i * 4);
    }

    f32x4 acc[4][4];
#pragma unroll
    for (int i = 0; i < 4; ++i)
#pragma unroll
        for (int j = 0; j < 4; ++j)
#pragma unroll
            for (int k = 0; k < 4; ++k) acc[i][j][k] = 0.f;

    const short* Ab = As + (wr * 64 + lc) * 40 + kg * 8;
    const short* Bb = Bs + (wc * 64 + lc) * 40 + kg * 8;

    for (int kt = 0; kt < NK / 32; ++kt) {
        __syncthreads();
        s16x8 va0, va1, vb0, vb1;
#pragma unroll
        for (int i = 0; i < 8; ++i) {
            va0[i] = f2bf(ra[i >> 2][i & 3]);
            va1[i] = f2bf(ra[2 + (i >> 2)][i & 3]);
            vb0[i] = f2bf(rb[i >> 2][i & 3]);
            vb1[i] = f2bf(rb[2 + (i >> 2)][i & 3]);
        }
        *(s16x8*)&As[sbase]     = va0;
        *(s16x8*)&As[sbase + 8] = va1;
        *(s16x8*)&Bs[sbase]     = vb0;
        *(s16x8*)&Bs[sbase + 8] = vb1;
        __syncthreads();

        if (kt + 1 < NK / 32) {
            const float* qA = pA + (kt + 1) * 32;
            const float* qB = pB + (kt + 1) * 32;
#pragma unroll
            for (int i = 0; i < 4; ++i) {
                ra[i] = *(const f32x4*)(qA + i * 4);
                rb[i] = *(const f32x4*)(qB + i * 4);
            }
        }

        s16x8 af[4], bfv[4];
#pragma unroll
        for (int mi = 0; mi < 4; ++mi) af[mi]  = *(const s16x8*)(Ab + mi * 16 * 40);
#pragma unroll
        for (int ni = 0; ni < 4; ++ni) bfv[ni] = *(const s16x8*)(Bb + ni * 16 * 40);
#pragma unroll
        for (int mi = 0; mi < 4; ++mi)
#pragma unroll
            for (int ni = 0; ni < 4; ++ni)
                acc[mi][ni] = __builtin_amdgcn_mfma_f32_16x16x32_bf16(
                    af[mi], bfv[ni], acc[mi][ni], 0, 0, 0);
    }

    rbf_epilogue(acc, x2, c2, ls, fcw, out, bm, bn, wr, wc, lc, kg);
}

// ---------------------------------------------------------------------------
extern "C" void kernel_launch(void* const* d_in, const int* in_sizes, int n_in,
                              void* d_out, int out_size, void* d_ws, size_t ws_size,
                              hipStream_t stream) {
    const float* X   = (const float*)d_in[0];   // [16384, 512]
    const float* Cn  = (const float*)d_in[1];   // [1024, 512]
    const float* ls  = (const float*)d_in[2];   // [1024]
    const float* fcw = (const float*)d_in[3];   // [5, 1024]
    const float* fcb = (const float*)d_in[4];   // [5]
    float* out = (float*)d_out;                 // [16384, 5]

    const size_t xbf_b = (size_t)NB * NK * 2;   // 16.78 MB
    const size_t cbf_b = (size_t)NO * NK * 2;   //  1.05 MB
    const size_t need  = xbf_b + cbf_b + (NB + NO) * sizeof(float);

    init_out<<<(NB * NC + 255) / 256, 256, 0, stream>>>(out, fcb);

    if (ws_size >= need) {
        short* xbf = (short*)d_ws;
        short* cbf = xbf + (size_t)NB * NK;
        float* x2  = (float*)(cbf + (size_t)NO * NK);
        float* c2  = x2 + NB;
        prep_bf16<<<(NB + NO + 3) / 4, 256, 0, stream>>>(X, Cn, xbf, cbf, x2, c2);
        dim3 grid(NO / 128, NB / 128);
        rbf_gemm_bf16<<<grid, 256, 0, stream>>>(xbf, cbf, x2, c2, ls, fcw, out);
    } else {
        float* x2 = (float*)d_ws;
        float* c2 = x2 + NB;
        prep_f32<<<(NB + NO + 3) / 4, 256, 0, stream>>>(X, Cn, x2, c2);
        dim3 grid(NO / 128, NB / 128);
        rbf_gemm_f32<<<grid, 256, 0, stream>>>(X, Cn, x2, c2, ls, fcw, out);
    }
}